// Round 1
// baseline (2287.206 us; speedup 1.0000x reference)
//
#include <hip/hip_runtime.h>
#include <hip/hip_bf16.h>

// Differential multi-head self-attention, MI355X bf16 MFMA pipeline.
// B=2 S=2048 E=512 H=8 D=512, half=256, scale=1/16 (folded into q cast).

typedef __attribute__((ext_vector_type(8))) short short8_t;   // 8 bf16
typedef __attribute__((ext_vector_type(4))) float f32x4;

__device__ __forceinline__ f32x4 mfma16(short8_t a, short8_t b, f32x4 c) {
    return __builtin_amdgcn_mfma_f32_16x16x32_bf16(a, b, c, 0, 0, 0);
}

__device__ __forceinline__ float grp16_max(float v) {
    v = fmaxf(v, __shfl_xor(v, 1));
    v = fmaxf(v, __shfl_xor(v, 2));
    v = fmaxf(v, __shfl_xor(v, 4));
    v = fmaxf(v, __shfl_xor(v, 8));
    return v;
}
__device__ __forceinline__ float grp16_sum(float v) {
    v += __shfl_xor(v, 1);
    v += __shfl_xor(v, 2);
    v += __shfl_xor(v, 4);
    v += __shfl_xor(v, 8);
    return v;
}

// ---------------- small prep kernels ----------------

__global__ void cast_x_kernel(const float* __restrict__ in, __hip_bfloat16* __restrict__ out) {
    const int i = (blockIdx.x * 256 + threadIdx.x) * 4;
    const float4 v = *reinterpret_cast<const float4*>(in + i);
    __align__(8) __hip_bfloat16 t[4];
    t[0] = __float2bfloat16(v.x); t[1] = __float2bfloat16(v.y);
    t[2] = __float2bfloat16(v.z); t[3] = __float2bfloat16(v.w);
    *reinterpret_cast<ushort4*>(out + i) = *reinterpret_cast<const ushort4*>(t);
}

// in: batch x R x C fp32  ->  out: batch x C x R bf16
__global__ void transpose_cast(const float* __restrict__ in, __hip_bfloat16* __restrict__ out,
                               int R, int C) {
    __shared__ float tile[32][33];
    const int c0 = blockIdx.x * 32, r0 = blockIdx.y * 32;
    const size_t boff = (size_t)blockIdx.z * R * C;
    const int tx = threadIdx.x & 31, ty = threadIdx.x >> 5; // ty 0..7
#pragma unroll
    for (int i = 0; i < 4; ++i)
        tile[ty + i * 8][tx] = in[boff + (size_t)(r0 + ty + i * 8) * C + c0 + tx];
    __syncthreads();
#pragma unroll
    for (int i = 0; i < 4; ++i)
        out[boff + (size_t)(c0 + ty + i * 8) * R + r0 + tx] = __float2bfloat16(tile[tx][ty + i * 8]);
}

__global__ void lam_kernel(const float* __restrict__ lq1, const float* __restrict__ lk1,
                           const float* __restrict__ lq2, const float* __restrict__ lk2,
                           const float* __restrict__ lam_init, float* __restrict__ lam) {
    const int h = blockIdx.x, l = threadIdx.x;
    float s1 = 0.f, s2 = 0.f;
    for (int j = l; j < 512; j += 64) {
        s1 += lq1[h * 512 + j] * lk1[h * 512 + j];
        s2 += lq2[h * 512 + j] * lk2[h * 512 + j];
    }
#pragma unroll
    for (int m = 1; m < 64; m <<= 1) { s1 += __shfl_xor(s1, m); s2 += __shfl_xor(s2, m); }
    if (l == 0) lam[h] = expf(s1) - expf(s2) + lam_init[h];
}

// ---------------- shared 128x128 GEMM core (bf16, B^T layout) ----------------
// A: [M][K] bf16, Bt: [N][K] bf16. Reg-staged, XOR-swizzled LDS ((row&7)<<4 on bytes):
// both staging writes and fragment reads are bank-uniform.

__device__ __forceinline__ void gemm_core(const __hip_bfloat16* __restrict__ A,
                                          const __hip_bfloat16* __restrict__ Bt,
                                          int Kdim, int m0, int n0,
                                          __hip_bfloat16* As, __hip_bfloat16* Bs,
                                          f32x4 acc[4][4]) {
    const int tid = threadIdx.x;
    const int lane = tid & 63;
    const int r16 = lane & 15, g4 = lane >> 4;
    const int wave = tid >> 6, wm = wave & 1, wn = wave >> 1;
    const int srow = tid >> 3;            // 0..31
    const int scol = (tid & 7) * 8;       // 0..56

    for (int k0 = 0; k0 < Kdim; k0 += 64) {
        __syncthreads();
#pragma unroll
        for (int rr = 0; rr < 4; ++rr) {
            const int row = srow + rr * 32;
            short8_t av = *reinterpret_cast<const short8_t*>(A + (size_t)(m0 + row) * Kdim + k0 + scol);
            short8_t bv = *reinterpret_cast<const short8_t*>(Bt + (size_t)(n0 + row) * Kdim + k0 + scol);
            const int wb = (row * 128 + scol * 2) ^ ((row & 7) << 4);
            *reinterpret_cast<short8_t*>((char*)As + wb) = av;
            *reinterpret_cast<short8_t*>((char*)Bs + wb) = bv;
        }
        __syncthreads();
#pragma unroll
        for (int kc = 0; kc < 2; ++kc) {
            short8_t aF[4], bF[4];
#pragma unroll
            for (int i = 0; i < 4; ++i) {
                const int arow = wm * 64 + i * 16 + r16;
                aF[i] = *reinterpret_cast<const short8_t*>(
                    (char*)As + ((arow * 128 + kc * 64 + g4 * 16) ^ ((arow & 7) << 4)));
                const int brow = wn * 64 + i * 16 + r16;
                bF[i] = *reinterpret_cast<const short8_t*>(
                    (char*)Bs + ((brow * 128 + kc * 64 + g4 * 16) ^ ((brow & 7) << 4)));
            }
#pragma unroll
            for (int i = 0; i < 4; ++i)
#pragma unroll
                for (int j = 0; j < 4; ++j)
                    acc[i][j] = mfma16(aF[i], bF[j], acc[i][j]);
        }
    }
}

// QKV projection: xb[4096][512] x wqkv_t[12288][512] -> q/k/v [B][H][S][D] bf16.
// q is pre-scaled by 1/16 (exact power of two).
__global__ __launch_bounds__(256, 2)
void gemm_qkv_kernel(const __hip_bfloat16* __restrict__ xb,
                     const __hip_bfloat16* __restrict__ wt,
                     const float* __restrict__ bq, const float* __restrict__ bk,
                     const float* __restrict__ bv,
                     __hip_bfloat16* __restrict__ qo, __hip_bfloat16* __restrict__ ko,
                     __hip_bfloat16* __restrict__ vo) {
    __shared__ __align__(16) __hip_bfloat16 As[128 * 64];
    __shared__ __align__(16) __hip_bfloat16 Bs[128 * 64];
    f32x4 acc[4][4];
    const f32x4 z4 = {0.f, 0.f, 0.f, 0.f};
#pragma unroll
    for (int i = 0; i < 4; ++i)
#pragma unroll
        for (int j = 0; j < 4; ++j) acc[i][j] = z4;

    const int m0 = blockIdx.x * 128;
    const int nt = blockIdx.y;
    gemm_core(xb, wt, 512, m0, nt * 128, As, Bs, acc);

    const int which = nt >> 5, hh = (nt >> 2) & 7, dbase = (nt & 3) * 128;
    __hip_bfloat16* outp = which == 0 ? qo : (which == 1 ? ko : vo);
    const float* bp = which == 0 ? bq : (which == 1 ? bk : bv);
    const float mul = which == 0 ? 0.0625f : 1.0f;

    const int tid = threadIdx.x, lane = tid & 63, wave = tid >> 6;
    const int r16 = lane & 15, g4 = lane >> 4, wm = wave & 1, wn = wave >> 1;
#pragma unroll
    for (int i = 0; i < 4; ++i) {
#pragma unroll
        for (int j = 0; j < 4; ++j) {
            const int d = dbase + wn * 64 + j * 16 + r16;
            const float bias = bp[hh * 512 + d];
#pragma unroll
            for (int r = 0; r < 4; ++r) {
                const int m = m0 + wm * 64 + i * 16 + g4 * 4 + r;
                const int b = m >> 11, s = m & 2047;
                outp[((size_t)(b * 8 + hh) * 2048 + s) * 512 + d] =
                    __float2bfloat16((acc[i][j][r] + bias) * mul);
            }
        }
    }
}

// Output projection: o_attn[4096][4096] x wo_t[512][4096] -> out fp32 [4096][512] (+bo)
__global__ __launch_bounds__(256, 2)
void gemm_out_kernel(const __hip_bfloat16* __restrict__ oa,
                     const __hip_bfloat16* __restrict__ wot,
                     const float* __restrict__ bo,
                     float* __restrict__ out) {
    __shared__ __align__(16) __hip_bfloat16 As[128 * 64];
    __shared__ __align__(16) __hip_bfloat16 Bs[128 * 64];
    f32x4 acc[4][4];
    const f32x4 z4 = {0.f, 0.f, 0.f, 0.f};
#pragma unroll
    for (int i = 0; i < 4; ++i)
#pragma unroll
        for (int j = 0; j < 4; ++j) acc[i][j] = z4;

    const int m0 = blockIdx.x * 128, n0 = blockIdx.y * 128;
    gemm_core(oa, wot, 4096, m0, n0, As, Bs, acc);

    const int tid = threadIdx.x, lane = tid & 63, wave = tid >> 6;
    const int r16 = lane & 15, g4 = lane >> 4, wm = wave & 1, wn = wave >> 1;
#pragma unroll
    for (int i = 0; i < 4; ++i) {
#pragma unroll
        for (int j = 0; j < 4; ++j) {
            const int n = n0 + wn * 64 + j * 16 + r16;
            const float bias = bo[n];
#pragma unroll
            for (int r = 0; r < 4; ++r) {
                const int m = m0 + wm * 64 + i * 16 + g4 * 4 + r;
                out[(size_t)m * 512 + n] = acc[i][j][r] + bias;
            }
        }
    }
}

// ---------------- differential flash attention ----------------
// grid (S/32=64, B*H=16), 256 threads (4 waves).
// waves 0,1: s1 rows 0-15/16-31 (d 0..255); waves 2,3: s2 (d 256..511).
// Each wave also owns a 128-wide D-slice of both O accumulators.

__global__ __launch_bounds__(256, 2)
void attn_kernel(const __hip_bfloat16* __restrict__ qg,
                 const __hip_bfloat16* __restrict__ kg,
                 const __hip_bfloat16* __restrict__ vg,
                 const float* __restrict__ lam,
                 const float* __restrict__ rms_w,
                 __hip_bfloat16* __restrict__ o_attn) {
    __shared__ __align__(16) __hip_bfloat16 Ks[32 * 512];        // XOR-swizzled rows
    __shared__ __align__(16) __hip_bfloat16 Vt2[4 * 512 * 8];    // [t>>3][d ^ thi][t&7]
    __shared__ __align__(16) __hip_bfloat16 P1[32 * 40];
    __shared__ __align__(16) __hip_bfloat16 P2[32 * 40];
    __shared__ float F1[32], F2[32], L1[32], L2[32], SSQ[4][32];

    const int tid = threadIdx.x;
    const int wave = tid >> 6, lane = tid & 63;
    const int r16 = lane & 15, g4 = lane >> 4;
    const int qtile = blockIdx.x, bh = blockIdx.y;
    const int h = bh & 7;
    const int q0 = qtile * 32;
    const int mat = wave >> 1, wrow = wave & 1;
    const size_t bh_off = (size_t)bh * 2048 * 512;

    // Q fragments: 16 rows x 256 d (this wave's half), k-chunks of 32
    short8_t qA[8];
    {
        const int row = q0 + wrow * 16 + r16;
        const __hip_bfloat16* qp = qg + bh_off + (size_t)row * 512 + mat * 256 + g4 * 8;
#pragma unroll
        for (int kk = 0; kk < 8; ++kk)
            qA[kk] = *reinterpret_cast<const short8_t*>(qp + kk * 32);
    }

    f32x4 O1[2][8], O2[2][8];
    const f32x4 z4 = {0.f, 0.f, 0.f, 0.f};
#pragma unroll
    for (int mq = 0; mq < 2; ++mq)
#pragma unroll
        for (int n = 0; n < 8; ++n) { O1[mq][n] = z4; O2[mq][n] = z4; }

    float m_run[4], l_run[4];
#pragma unroll
    for (int r = 0; r < 4; ++r) { m_run[r] = -1e30f; l_run[r] = 0.f; }

    const int st_t = tid >> 3;        // 0..31
    const int st_d = (tid & 7) * 8;   // 0..56
    const int thi = st_t >> 3, tlo = st_t & 7;

    const int nkv = qtile + 1;
    for (int it = 0; it < nkv; ++it) {
        const int kv0 = it * 32;
        __syncthreads();   // previous iteration's PV reads done before restaging
        {
            const __hip_bfloat16* kp = kg + bh_off + (size_t)(kv0 + st_t) * 512 + st_d;
            const __hip_bfloat16* vp = vg + bh_off + (size_t)(kv0 + st_t) * 512 + st_d;
#pragma unroll
            for (int pass = 0; pass < 8; ++pass) {
                short8_t k8 = *reinterpret_cast<const short8_t*>(kp + pass * 64);
                const int wb = ((st_t * 512 + st_d + pass * 64) * 2) ^ ((st_t & 7) << 4);
                *reinterpret_cast<short8_t*>((char*)Ks + wb) = k8;
                short8_t v8 = *reinterpret_cast<const short8_t*>(vp + pass * 64);
#pragma unroll
                for (int j = 0; j < 8; ++j) {
                    const int d = st_d + pass * 64 + j;
                    reinterpret_cast<short*>(Vt2)[(thi * 512 + (d ^ thi)) * 8 + tlo] = v8[j];
                }
            }
        }
        __syncthreads();

        // scores for this wave's 16 rows (2 col-frags) over its d-half
        f32x4 sc0 = z4, sc1 = z4;
#pragma unroll
        for (int kk = 0; kk < 8; ++kk) {
            const int d = mat * 256 + kk * 32 + g4 * 8;
            const int b0 = ((r16 * 512 + d) * 2) ^ ((r16 & 7) << 4);
            short8_t kf0 = *reinterpret_cast<const short8_t*>((char*)Ks + b0);
            sc0 = mfma16(qA[kk], kf0, sc0);
            const int trow = 16 + r16;
            const int b1 = ((trow * 512 + d) * 2) ^ ((trow & 7) << 4);
            short8_t kf1 = *reinterpret_cast<const short8_t*>((char*)Ks + b1);
            sc1 = mfma16(qA[kk], kf1, sc1);
        }

        // causal mask + online softmax (rows owned wave-locally)
        const int srow_base = q0 + wrow * 16 + g4 * 4;
        float tmax[4];
#pragma unroll
        for (int r = 0; r < 4; ++r) {
            float x0 = sc0[r], x1 = sc1[r];
            const int srow = srow_base + r;
            if (kv0 + r16 > srow)      x0 = -1e30f;
            if (kv0 + 16 + r16 > srow) x1 = -1e30f;
            sc0[r] = x0; sc1[r] = x1;
            tmax[r] = grp16_max(fmaxf(x0, x1));
        }
        float fr[4], rs[4];
#pragma unroll
        for (int r = 0; r < 4; ++r) {
            const float mnew = fmaxf(m_run[r], tmax[r]);
            fr[r] = __expf(m_run[r] - mnew);
            m_run[r] = mnew;
            const float e0 = __expf(sc0[r] - mnew);
            const float e1 = __expf(sc1[r] - mnew);
            sc0[r] = e0; sc1[r] = e1;
            rs[r] = grp16_sum(e0 + e1);
            l_run[r] = l_run[r] * fr[r] + rs[r];
        }
        __hip_bfloat16* Pm = (mat == 0) ? P1 : P2;
        float* Fm = (mat == 0) ? F1 : F2;
#pragma unroll
        for (int r = 0; r < 4; ++r) {
            const int prow = wrow * 16 + g4 * 4 + r;
            Pm[prow * 40 + r16]      = __float2bfloat16(sc0[r]);
            Pm[prow * 40 + 16 + r16] = __float2bfloat16(sc1[r]);
            if (r16 == 0) Fm[prow] = fr[r];
        }
        __syncthreads();

        // PV: each wave does its 128-wide D slice for both mats
        short8_t pa1[2], pa2[2];
#pragma unroll
        for (int mq = 0; mq < 2; ++mq) {
            pa1[mq] = *reinterpret_cast<const short8_t*>(
                (const char*)P1 + ((mq * 16 + r16) * 40 + g4 * 8) * 2);
            pa2[mq] = *reinterpret_cast<const short8_t*>(
                (const char*)P2 + ((mq * 16 + r16) * 40 + g4 * 8) * 2);
        }
        float f1v[2][4], f2v[2][4];
#pragma unroll
        for (int mq = 0; mq < 2; ++mq)
#pragma unroll
            for (int r = 0; r < 4; ++r) {
                const int rm = mq * 16 + g4 * 4 + r;
                f1v[mq][r] = F1[rm];
                f2v[mq][r] = F2[rm];
            }
#pragma unroll
        for (int mq = 0; mq < 2; ++mq)
#pragma unroll
            for (int r = 0; r < 4; ++r) {
                const float f = f1v[mq][r];
                if (f != 1.0f) {
#pragma unroll
                    for (int n = 0; n < 8; ++n) O1[mq][n][r] *= f;
                }
                const float g = f2v[mq][r];
                if (g != 1.0f) {
#pragma unroll
                    for (int n = 0; n < 8; ++n) O2[mq][n][r] *= g;
                }
            }
#pragma unroll
        for (int n = 0; n < 8; ++n) {
            const int d = wave * 128 + n * 16 + r16;
            short8_t vb = *reinterpret_cast<const short8_t*>(
                (const char*)Vt2 + (g4 * 512 + (d ^ g4)) * 16);
#pragma unroll
            for (int mq = 0; mq < 2; ++mq) {
                O1[mq][n] = mfma16(pa1[mq], vb, O1[mq][n]);
                O2[mq][n] = mfma16(pa2[mq], vb, O2[mq][n]);
            }
        }
    }

    // epilogue: publish l, combine, RMS norm, write bf16 o_attn [B,S,H*D]
    {
        float* Lm = (mat == 0) ? L1 : L2;
        if (r16 == 0) {
#pragma unroll
            for (int r = 0; r < 4; ++r) Lm[wrow * 16 + g4 * 4 + r] = l_run[r];
        }
    }
    __syncthreads();
    const float lam_h = lam[h];
    float inv1[2][4], inv2[2][4];
#pragma unroll
    for (int mq = 0; mq < 2; ++mq)
#pragma unroll
        for (int r = 0; r < 4; ++r) {
            const int rm = mq * 16 + g4 * 4 + r;
            inv1[mq][r] = 1.0f / L1[rm];
            inv2[mq][r] = lam_h / L2[rm];
        }
    float ssq[2][4];
#pragma unroll
    for (int mq = 0; mq < 2; ++mq)
#pragma unroll
        for (int r = 0; r < 4; ++r) ssq[mq][r] = 0.f;
#pragma unroll
    for (int mq = 0; mq < 2; ++mq)
#pragma unroll
        for (int n = 0; n < 8; ++n)
#pragma unroll
            for (int r = 0; r < 4; ++r) {
                const float val = O1[mq][n][r] * inv1[mq][r] - O2[mq][n][r] * inv2[mq][r];
                O1[mq][n][r] = val;
                ssq[mq][r] += val * val;
            }
#pragma unroll
    for (int mq = 0; mq < 2; ++mq)
#pragma unroll
        for (int r = 0; r < 4; ++r) {
            ssq[mq][r] = grp16_sum(ssq[mq][r]);
            if (r16 == 0) SSQ[wave][mq * 16 + g4 * 4 + r] = ssq[mq][r];
        }
    __syncthreads();
    float rsc[2][4];
#pragma unroll
    for (int mq = 0; mq < 2; ++mq)
#pragma unroll
        for (int r = 0; r < 4; ++r) {
            const int rm = mq * 16 + g4 * 4 + r;
            const float tot = SSQ[0][rm] + SSQ[1][rm] + SSQ[2][rm] + SSQ[3][rm];
            rsc[mq][r] = rsqrtf(tot * (1.0f / 512.0f) + 1.1920929e-7f) * (1.0f - 0.8f);
        }
    const int b = bh >> 3;
#pragma unroll
    for (int n = 0; n < 8; ++n) {
        const int d = wave * 128 + n * 16 + r16;
        const float rw = rms_w[h * 512 + d];
#pragma unroll
        for (int mq = 0; mq < 2; ++mq)
#pragma unroll
            for (int r = 0; r < 4; ++r) {
                const int srow = q0 + mq * 16 + g4 * 4 + r;
                o_attn[(size_t)(b * 2048 + srow) * 4096 + h * 512 + d] =
                    __float2bfloat16(O1[mq][n][r] * rsc[mq][r] * rw);
            }
    }
}

// ---------------- launch ----------------

extern "C" void kernel_launch(void* const* d_in, const int* in_sizes, int n_in,
                              void* d_out, int out_size, void* d_ws, size_t ws_size,
                              hipStream_t stream) {
    const float* x    = (const float*)d_in[0];
    const float* Wq   = (const float*)d_in[2];
    const float* bq   = (const float*)d_in[3];
    const float* Wk   = (const float*)d_in[4];
    const float* bk   = (const float*)d_in[5];
    const float* Wv   = (const float*)d_in[6];
    const float* bv   = (const float*)d_in[7];
    const float* lq1  = (const float*)d_in[8];
    const float* lk1  = (const float*)d_in[9];
    const float* lq2  = (const float*)d_in[10];
    const float* lk2  = (const float*)d_in[11];
    const float* lamI = (const float*)d_in[12];
    const float* rmsw = (const float*)d_in[13];
    const float* Wo   = (const float*)d_in[14];
    const float* bo   = (const float*)d_in[15];

    char* w = (char*)d_ws;
    __hip_bfloat16* xb     = (__hip_bfloat16*)(w);                 //  4,194,304
    __hip_bfloat16* wqkv_t = (__hip_bfloat16*)(w + 4194304);       // 12,582,912
    __hip_bfloat16* wo_t   = (__hip_bfloat16*)(w + 16777216);      //  4,194,304
    __hip_bfloat16* qws    = (__hip_bfloat16*)(w + 20971520);      // 33,554,432
    __hip_bfloat16* kws    = (__hip_bfloat16*)(w + 54525952);      // 33,554,432
    __hip_bfloat16* vws    = (__hip_bfloat16*)(w + 88080384);      // 33,554,432
    __hip_bfloat16* oa     = (__hip_bfloat16*)(w + 121634816);     // 33,554,432
    float*          lamp   = (float*)(w + 155189248);              // 32

    cast_x_kernel<<<2048, 256, 0, stream>>>(x, xb);
    transpose_cast<<<dim3(16, 16, 8), 256, 0, stream>>>(Wq, wqkv_t,           512, 512);
    transpose_cast<<<dim3(16, 16, 8), 256, 0, stream>>>(Wk, wqkv_t + 2097152, 512, 512);
    transpose_cast<<<dim3(16, 16, 8), 256, 0, stream>>>(Wv, wqkv_t + 4194304, 512, 512);
    transpose_cast<<<dim3(16, 128, 1), 256, 0, stream>>>(Wo, wo_t, 4096, 512);
    lam_kernel<<<8, 64, 0, stream>>>(lq1, lk1, lq2, lk2, lamI, lamp);

    gemm_qkv_kernel<<<dim3(32, 96), 256, 0, stream>>>(xb, wqkv_t, bq, bk, bv, qws, kws, vws);
    attn_kernel<<<dim3(64, 16), 256, 0, stream>>>(qws, kws, vws, lamp, rmsw, oa);
    gemm_out_kernel<<<dim3(32, 4), 256, 0, stream>>>(oa, wo_t, bo, (float*)d_out);
}

// Round 4
// 2042.142 us; speedup vs baseline: 1.1200x; 1.1200x over previous
//
#include <hip/hip_runtime.h>
#include <hip/hip_bf16.h>

// Differential multi-head self-attention, MI355X bf16 MFMA pipeline.
// B=2 S=2048 E=512 H=8 D=512, half=256, scale=1/16 (folded into q cast).

typedef __attribute__((ext_vector_type(8))) short short8_t;   // 8 bf16
typedef __attribute__((ext_vector_type(4))) float f32x4;

#define AS1 __attribute__((address_space(1)))
#define AS3 __attribute__((address_space(3)))

__device__ __forceinline__ f32x4 mfma16(short8_t a, short8_t b, f32x4 c) {
    return __builtin_amdgcn_mfma_f32_16x16x32_bf16(a, b, c, 0, 0, 0);
}

__device__ __forceinline__ float grp16_max(float v) {
    v = fmaxf(v, __shfl_xor(v, 1));
    v = fmaxf(v, __shfl_xor(v, 2));
    v = fmaxf(v, __shfl_xor(v, 4));
    v = fmaxf(v, __shfl_xor(v, 8));
    return v;
}
__device__ __forceinline__ float grp16_sum(float v) {
    v += __shfl_xor(v, 1);
    v += __shfl_xor(v, 2);
    v += __shfl_xor(v, 4);
    v += __shfl_xor(v, 8);
    return v;
}

// ---------------- small prep kernels ----------------

__global__ void cast_x_kernel(const float* __restrict__ in, __hip_bfloat16* __restrict__ out) {
    const int i = (blockIdx.x * 256 + threadIdx.x) * 4;
    const float4 v = *reinterpret_cast<const float4*>(in + i);
    __align__(8) __hip_bfloat16 t[4];
    t[0] = __float2bfloat16(v.x); t[1] = __float2bfloat16(v.y);
    t[2] = __float2bfloat16(v.z); t[3] = __float2bfloat16(v.w);
    *reinterpret_cast<ushort4*>(out + i) = *reinterpret_cast<const ushort4*>(t);
}

// in: batch x R x C fp32  ->  out: batch x C x R bf16
__global__ void transpose_cast(const float* __restrict__ in, __hip_bfloat16* __restrict__ out,
                               int R, int C) {
    __shared__ float tile[32][33];
    const int c0 = blockIdx.x * 32, r0 = blockIdx.y * 32;
    const size_t boff = (size_t)blockIdx.z * R * C;
    const int tx = threadIdx.x & 31, ty = threadIdx.x >> 5; // ty 0..7
#pragma unroll
    for (int i = 0; i < 4; ++i)
        tile[ty + i * 8][tx] = in[boff + (size_t)(r0 + ty + i * 8) * C + c0 + tx];
    __syncthreads();
#pragma unroll
    for (int i = 0; i < 4; ++i)
        out[boff + (size_t)(c0 + ty + i * 8) * R + r0 + tx] = __float2bfloat16(tile[tx][ty + i * 8]);
}

__global__ void lam_kernel(const float* __restrict__ lq1, const float* __restrict__ lk1,
                           const float* __restrict__ lq2, const float* __restrict__ lk2,
                           const float* __restrict__ lam_init, float* __restrict__ lam) {
    const int h = blockIdx.x, l = threadIdx.x;
    float s1 = 0.f, s2 = 0.f;
    for (int j = l; j < 512; j += 64) {
        s1 += lq1[h * 512 + j] * lk1[h * 512 + j];
        s2 += lq2[h * 512 + j] * lk2[h * 512 + j];
    }
#pragma unroll
    for (int m = 1; m < 64; m <<= 1) { s1 += __shfl_xor(s1, m); s2 += __shfl_xor(s2, m); }
    if (l == 0) lam[h] = expf(s1) - expf(s2) + lam_init[h];
}

// ---------------- shared 128x128 GEMM core (bf16, B^T layout) ----------------

__device__ __forceinline__ void gemm_core(const __hip_bfloat16* __restrict__ A,
                                          const __hip_bfloat16* __restrict__ Bt,
                                          int Kdim, int m0, int n0,
                                          __hip_bfloat16* As, __hip_bfloat16* Bs,
                                          f32x4 acc[4][4]) {
    const int tid = threadIdx.x;
    const int lane = tid & 63;
    const int r16 = lane & 15, g4 = lane >> 4;
    const int wave = tid >> 6, wm = wave & 1, wn = wave >> 1;
    const int srow = tid >> 3;            // 0..31
    const int scol = (tid & 7) * 8;       // 0..56

    for (int k0 = 0; k0 < Kdim; k0 += 64) {
        __syncthreads();
#pragma unroll
        for (int rr = 0; rr < 4; ++rr) {
            const int row = srow + rr * 32;
            short8_t av = *reinterpret_cast<const short8_t*>(A + (size_t)(m0 + row) * Kdim + k0 + scol);
            short8_t bv = *reinterpret_cast<const short8_t*>(Bt + (size_t)(n0 + row) * Kdim + k0 + scol);
            const int wb = (row * 128 + scol * 2) ^ ((row & 7) << 4);
            *reinterpret_cast<short8_t*>((char*)As + wb) = av;
            *reinterpret_cast<short8_t*>((char*)Bs + wb) = bv;
        }
        __syncthreads();
#pragma unroll
        for (int kc = 0; kc < 2; ++kc) {
            short8_t aF[4], bF[4];
#pragma unroll
            for (int i = 0; i < 4; ++i) {
                const int arow = wm * 64 + i * 16 + r16;
                aF[i] = *reinterpret_cast<const short8_t*>(
                    (char*)As + ((arow * 128 + kc * 64 + g4 * 16) ^ ((arow & 7) << 4)));
                const int brow = wn * 64 + i * 16 + r16;
                bF[i] = *reinterpret_cast<const short8_t*>(
                    (char*)Bs + ((brow * 128 + kc * 64 + g4 * 16) ^ ((brow & 7) << 4)));
            }
#pragma unroll
            for (int i = 0; i < 4; ++i)
#pragma unroll
                for (int j = 0; j < 4; ++j)
                    acc[i][j] = mfma16(aF[i], bF[j], acc[i][j]);
        }
    }
}

// QKV projection: xb[4096][512] x wqkv_t[12288][512] -> q,k [B*H][S][D], v^T [B*H][D][S] (bf16).
// q is pre-scaled by 1/16.
__global__ __launch_bounds__(256, 2)
void gemm_qkv_kernel(const __hip_bfloat16* __restrict__ xb,
                     const __hip_bfloat16* __restrict__ wt,
                     const float* __restrict__ bq, const float* __restrict__ bk,
                     const float* __restrict__ bv,
                     __hip_bfloat16* __restrict__ qo, __hip_bfloat16* __restrict__ ko,
                     __hip_bfloat16* __restrict__ vo) {
    __shared__ __align__(16) __hip_bfloat16 As[128 * 64];
    __shared__ __align__(16) __hip_bfloat16 Bs[128 * 64];
    f32x4 acc[4][4];
    const f32x4 z4 = {0.f, 0.f, 0.f, 0.f};
#pragma unroll
    for (int i = 0; i < 4; ++i)
#pragma unroll
        for (int j = 0; j < 4; ++j) acc[i][j] = z4;

    const int m0 = blockIdx.x * 128;
    const int nt = blockIdx.y;
    gemm_core(xb, wt, 512, m0, nt * 128, As, Bs, acc);

    const int which = nt >> 5, hh = (nt >> 2) & 7, dbase = (nt & 3) * 128;
    const int tid = threadIdx.x, lane = tid & 63, wave = tid >> 6;
    const int r16 = lane & 15, g4 = lane >> 4, wm = wave & 1, wn = wave >> 1;
    const int b = m0 >> 11;

    if (which == 2) {
        // V^T: [b*8+h][d][s], 4 consecutive s per fragment -> ushort4 store
#pragma unroll
        for (int i = 0; i < 4; ++i) {
#pragma unroll
            for (int j = 0; j < 4; ++j) {
                const int d = dbase + wn * 64 + j * 16 + r16;
                const float bias = bv[hh * 512 + d];
                const int s0 = (m0 & 2047) + wm * 64 + i * 16 + g4 * 4;
                __align__(8) __hip_bfloat16 t4[4];
#pragma unroll
                for (int r = 0; r < 4; ++r) t4[r] = __float2bfloat16(acc[i][j][r] + bias);
                *reinterpret_cast<ushort4*>(vo + ((size_t)(b * 8 + hh) * 512 + d) * 2048 + s0) =
                    *reinterpret_cast<const ushort4*>(t4);
            }
        }
    } else {
        __hip_bfloat16* outp = which == 0 ? qo : ko;
        const float* bp = which == 0 ? bq : bk;
        const float mul = which == 0 ? 0.0625f : 1.0f;
#pragma unroll
        for (int i = 0; i < 4; ++i) {
#pragma unroll
            for (int j = 0; j < 4; ++j) {
                const int d = dbase + wn * 64 + j * 16 + r16;
                const float bias = bp[hh * 512 + d];
#pragma unroll
                for (int r = 0; r < 4; ++r) {
                    const int s = (m0 & 2047) + wm * 64 + i * 16 + g4 * 4 + r;
                    outp[((size_t)(b * 8 + hh) * 2048 + s) * 512 + d] =
                        __float2bfloat16((acc[i][j][r] + bias) * mul);
                }
            }
        }
    }
}

// Output projection: o_attn[4096][4096] x wo_t[512][4096] -> out fp32 [4096][512] (+bo)
__global__ __launch_bounds__(256, 2)
void gemm_out_kernel(const __hip_bfloat16* __restrict__ oa,
                     const __hip_bfloat16* __restrict__ wot,
                     const float* __restrict__ bo,
                     float* __restrict__ out) {
    __shared__ __align__(16) __hip_bfloat16 As[128 * 64];
    __shared__ __align__(16) __hip_bfloat16 Bs[128 * 64];
    f32x4 acc[4][4];
    const f32x4 z4 = {0.f, 0.f, 0.f, 0.f};
#pragma unroll
    for (int i = 0; i < 4; ++i)
#pragma unroll
        for (int j = 0; j < 4; ++j) acc[i][j] = z4;

    const int m0 = blockIdx.x * 128, n0 = blockIdx.y * 128;
    gemm_core(oa, wot, 4096, m0, n0, As, Bs, acc);

    const int tid = threadIdx.x, lane = tid & 63, wave = tid >> 6;
    const int r16 = lane & 15, g4 = lane >> 4, wm = wave & 1, wn = wave >> 1;
#pragma unroll
    for (int i = 0; i < 4; ++i) {
#pragma unroll
        for (int j = 0; j < 4; ++j) {
            const int n = n0 + wn * 64 + j * 16 + r16;
            const float bias = bo[n];
#pragma unroll
            for (int r = 0; r < 4; ++r) {
                const int m = m0 + wm * 64 + i * 16 + g4 * 4 + r;
                out[(size_t)m * 512 + n] = acc[i][j][r] + bias;
            }
        }
    }
}

// ---------------- differential flash attention ----------------
// grid (S/32=64, B*H=16), 256 threads (4 waves).
// waves 0,1: s1 rows 0-15/16-31 (d 0..255); waves 2,3: s2 (d 256..511).
// Each wave also owns a 128-wide D-slice of both O accumulators.
// K/V^T staged via global_load_lds (linear LDS dest, pre-swizzled global source).

__global__ __launch_bounds__(256, 2)
void attn_kernel(const __hip_bfloat16* __restrict__ qg,
                 const __hip_bfloat16* __restrict__ kg,
                 const __hip_bfloat16* __restrict__ vtg,
                 const float* __restrict__ lam,
                 const float* __restrict__ rms_w,
                 __hip_bfloat16* __restrict__ o_attn) {
    __shared__ __align__(16) __hip_bfloat16 Ks[32 * 512];   // [t][d], byte ^ ((t&7)<<4)
    __shared__ __align__(16) __hip_bfloat16 Vs[512 * 32];   // [d][t], byte ^ ((d&7)<<4)
    __shared__ __align__(16) __hip_bfloat16 P1[32 * 40];
    __shared__ __align__(16) __hip_bfloat16 P2[32 * 40];
    __shared__ float F1[32], F2[32], L1[32], L2[32], SSQ[4][32];

    const int tid = threadIdx.x;
    const int wave = tid >> 6, lane = tid & 63;
    const int r16 = lane & 15, g4 = lane >> 4;
    const int qtile = gridDim.x - 1 - blockIdx.x;   // long blocks first
    const int bh = blockIdx.y;
    const int h = bh & 7;
    const int q0 = qtile * 32;
    const int mat = wave >> 1, wrow = wave & 1;
    const size_t bh_off = (size_t)bh * 2048 * 512;

    // Q fragments: 16 rows x 256 d (this wave's half), k-chunks of 32
    short8_t qA[8];
    {
        const int row = q0 + wrow * 16 + r16;
        const __hip_bfloat16* qp = qg + bh_off + (size_t)row * 512 + mat * 256 + g4 * 8;
#pragma unroll
        for (int kk = 0; kk < 8; ++kk)
            qA[kk] = *reinterpret_cast<const short8_t*>(qp + kk * 32);
    }

    f32x4 O1[2][8], O2[2][8];
    const f32x4 z4 = {0.f, 0.f, 0.f, 0.f};
#pragma unroll
    for (int mq = 0; mq < 2; ++mq)
#pragma unroll
        for (int n = 0; n < 8; ++n) { O1[mq][n] = z4; O2[mq][n] = z4; }

    float m_run[4], l_run[4];
#pragma unroll
    for (int r = 0; r < 4; ++r) { m_run[r] = -1e30f; l_run[r] = 0.f; }

    // per-lane pre-swizzled global source offsets (elements)
    // V^T: lane i covers LDS (d'=i>>2, c'=i&3) of a 16-row group
    const int b2v = (lane >> 4) & 1;
    const int vdrel = (lane >> 2) ^ b2v;
    const int vcs = (lane & 3) ^ (((lane >> 2) & 3) ^ b2v);
    const int voff = vdrel * 2048 + vcs * 8;

    const int nkv = qtile + 1;
    for (int it = 0; it < nkv; ++it) {
        const int kv0 = it * 32;
        __syncthreads();   // previous iteration's reads done before restaging
        {
            const __hip_bfloat16* kbase = kg + bh_off + (size_t)kv0 * 512;
            const __hip_bfloat16* vbase = vtg + bh_off + kv0;
#pragma unroll
            for (int rr = 0; rr < 8; ++rr) {
                const int t = wave * 8 + rr;
                __builtin_amdgcn_global_load_lds(
                    (const AS1 void*)(kbase + (size_t)t * 512 + ((lane ^ rr) << 3)),
                    (AS3 void*)((char*)Ks + t * 1024), 16, 0, 0);
            }
#pragma unroll
            for (int p = 0; p < 8; ++p) {
                const int g = p * 4 + wave;
                __builtin_amdgcn_global_load_lds(
                    (const AS1 void*)(vbase + (size_t)g * 16 * 2048 + voff),
                    (AS3 void*)((char*)Vs + g * 1024), 16, 0, 0);
            }
        }
        __syncthreads();   // drains vmcnt(0): tiles ready

        // scores for this wave's 16 rows (2 col-frags) over its d-half
        f32x4 sc0 = z4, sc1 = z4;
#pragma unroll
        for (int kk = 0; kk < 8; ++kk) {
            const int d = mat * 256 + kk * 32 + g4 * 8;
            const int b0 = ((r16 * 512 + d) * 2) ^ ((r16 & 7) << 4);
            short8_t kf0 = *reinterpret_cast<const short8_t*>((char*)Ks + b0);
            sc0 = mfma16(qA[kk], kf0, sc0);
            const int trow = 16 + r16;
            const int b1 = ((trow * 512 + d) * 2) ^ ((trow & 7) << 4);
            short8_t kf1 = *reinterpret_cast<const short8_t*>((char*)Ks + b1);
            sc1 = mfma16(qA[kk], kf1, sc1);
        }

        // causal mask + online softmax (rows owned wave-locally)
        const int srow_base = q0 + wrow * 16 + g4 * 4;
        float tmax[4];
#pragma unroll
        for (int r = 0; r < 4; ++r) {
            float x0 = sc0[r], x1 = sc1[r];
            const int srow = srow_base + r;
            if (kv0 + r16 > srow)      x0 = -1e30f;
            if (kv0 + 16 + r16 > srow) x1 = -1e30f;
            sc0[r] = x0; sc1[r] = x1;
            tmax[r] = grp16_max(fmaxf(x0, x1));
        }
        float fr[4];
#pragma unroll
        for (int r = 0; r < 4; ++r) {
            const float mnew = fmaxf(m_run[r], tmax[r]);
            fr[r] = __expf(m_run[r] - mnew);
            m_run[r] = mnew;
            const float e0 = __expf(sc0[r] - mnew);
            const float e1 = __expf(sc1[r] - mnew);
            sc0[r] = e0; sc1[r] = e1;
            l_run[r] = l_run[r] * fr[r] + grp16_sum(e0 + e1);
        }
        __hip_bfloat16* Pm = (mat == 0) ? P1 : P2;
        float* Fm = (mat == 0) ? F1 : F2;
#pragma unroll
        for (int r = 0; r < 4; ++r) {
            const int prow = wrow * 16 + g4 * 4 + r;
            Pm[prow * 40 + r16]      = __float2bfloat16(sc0[r]);
            Pm[prow * 40 + 16 + r16] = __float2bfloat16(sc1[r]);
            if (r16 == 0) Fm[prow] = fr[r];
        }
        __syncthreads();

        // PV: each wave does its 128-wide D slice for both mats
        short8_t pa1[2], pa2[2];
#pragma unroll
        for (int mq = 0; mq < 2; ++mq) {
            pa1[mq] = *reinterpret_cast<const short8_t*>(
                (const char*)P1 + ((mq * 16 + r16) * 40 + g4 * 8) * 2);
            pa2[mq] = *reinterpret_cast<const short8_t*>(
                (const char*)P2 + ((mq * 16 + r16) * 40 + g4 * 8) * 2);
        }
        float f1v[2][4], f2v[2][4];
#pragma unroll
        for (int mq = 0; mq < 2; ++mq)
#pragma unroll
            for (int r = 0; r < 4; ++r) {
                const int rm = mq * 16 + g4 * 4 + r;
                f1v[mq][r] = F1[rm];
                f2v[mq][r] = F2[rm];
            }
#pragma unroll
        for (int mq = 0; mq < 2; ++mq)
#pragma unroll
            for (int r = 0; r < 4; ++r) {
                const float f = f1v[mq][r];
                if (f != 1.0f) {
#pragma unroll
                    for (int n = 0; n < 8; ++n) O1[mq][n][r] *= f;
                }
                const float g = f2v[mq][r];
                if (g != 1.0f) {
#pragma unroll
                    for (int n = 0; n < 8; ++n) O2[mq][n][r] *= g;
                }
            }
#pragma unroll
        for (int n = 0; n < 8; ++n) {
            const int d = wave * 128 + n * 16 + r16;
            const int rb = (d * 64 + g4 * 16) ^ ((r16 & 7) << 4);
            short8_t vb = *reinterpret_cast<const short8_t*>((const char*)Vs + rb);
#pragma unroll
            for (int mq = 0; mq < 2; ++mq) {
                O1[mq][n] = mfma16(pa1[mq], vb, O1[mq][n]);
                O2[mq][n] = mfma16(pa2[mq], vb, O2[mq][n]);
            }
        }
    }

    // epilogue: publish l, combine, RMS norm, write bf16 o_attn [B,S,H*D]
    {
        float* Lm = (mat == 0) ? L1 : L2;
        if (r16 == 0) {
#pragma unroll
            for (int r = 0; r < 4; ++r) Lm[wrow * 16 + g4 * 4 + r] = l_run[r];
        }
    }
    __syncthreads();
    const float lam_h = lam[h];
    float inv1[2][4], inv2[2][4];
#pragma unroll
    for (int mq = 0; mq < 2; ++mq)
#pragma unroll
        for (int r = 0; r < 4; ++r) {
            const int rm = mq * 16 + g4 * 4 + r;
            inv1[mq][r] = 1.0f / L1[rm];
            inv2[mq][r] = lam_h / L2[rm];
        }
    float ssq[2][4];
#pragma unroll
    for (int mq = 0; mq < 2; ++mq)
#pragma unroll
        for (int r = 0; r < 4; ++r) ssq[mq][r] = 0.f;
#pragma unroll
    for (int mq = 0; mq < 2; ++mq)
#pragma unroll
        for (int n = 0; n < 8; ++n)
#pragma unroll
            for (int r = 0; r < 4; ++r) {
                const float val = O1[mq][n][r] * inv1[mq][r] - O2[mq][n][r] * inv2[mq][r];
                O1[mq][n][r] = val;
                ssq[mq][r] += val * val;
            }
#pragma unroll
    for (int mq = 0; mq < 2; ++mq)
#pragma unroll
        for (int r = 0; r < 4; ++r) {
            ssq[mq][r] = grp16_sum(ssq[mq][r]);
            if (r16 == 0) SSQ[wave][mq * 16 + g4 * 4 + r] = ssq[mq][r];
        }
    __syncthreads();
    float rsc[2][4];
#pragma unroll
    for (int mq = 0; mq < 2; ++mq)
#pragma unroll
        for (int r = 0; r < 4; ++r) {
            const int rm = mq * 16 + g4 * 4 + r;
            const float tot = SSQ[0][rm] + SSQ[1][rm] + SSQ[2][rm] + SSQ[3][rm];
            rsc[mq][r] = rsqrtf(tot * (1.0f / 512.0f) + 1.1920929e-7f) * (1.0f - 0.8f);
        }
    const int b = bh >> 3;
#pragma unroll
    for (int n = 0; n < 8; ++n) {
        const int d = wave * 128 + n * 16 + r16;
        const float rw = rms_w[h * 512 + d];
#pragma unroll
        for (int mq = 0; mq < 2; ++mq)
#pragma unroll
            for (int r = 0; r < 4; ++r) {
                const int srow = q0 + mq * 16 + g4 * 4 + r;
                o_attn[(size_t)(b * 2048 + srow) * 4096 + h * 512 + d] =
                    __float2bfloat16(O1[mq][n][r] * rsc[mq][r] * rw);
            }
    }
}

// ---------------- launch ----------------

extern "C" void kernel_launch(void* const* d_in, const int* in_sizes, int n_in,
                              void* d_out, int out_size, void* d_ws, size_t ws_size,
                              hipStream_t stream) {
    const float* x    = (const float*)d_in[0];
    const float* Wq   = (const float*)d_in[2];
    const float* bq   = (const float*)d_in[3];
    const float* Wk   = (const float*)d_in[4];
    const float* bk   = (const float*)d_in[5];
    const float* Wv   = (const float*)d_in[6];
    const float* bv   = (const float*)d_in[7];
    const float* lq1  = (const float*)d_in[8];
    const float* lk1  = (const float*)d_in[9];
    const float* lq2  = (const float*)d_in[10];
    const float* lk2  = (const float*)d_in[11];
    const float* lamI = (const float*)d_in[12];
    const float* rmsw = (const float*)d_in[13];
    const float* Wo   = (const float*)d_in[14];
    const float* bo   = (const float*)d_in[15];

    char* w = (char*)d_ws;
    __hip_bfloat16* xb     = (__hip_bfloat16*)(w);                 //  4,194,304
    __hip_bfloat16* wqkv_t = (__hip_bfloat16*)(w + 4194304);       // 12,582,912
    __hip_bfloat16* wo_t   = (__hip_bfloat16*)(w + 16777216);      //  4,194,304
    __hip_bfloat16* qws    = (__hip_bfloat16*)(w + 20971520);      // 33,554,432
    __hip_bfloat16* kws    = (__hip_bfloat16*)(w + 54525952);      // 33,554,432
    __hip_bfloat16* vtws   = (__hip_bfloat16*)(w + 88080384);      // 33,554,432 (V^T)
    __hip_bfloat16* oa     = (__hip_bfloat16*)(w + 121634816);     // 33,554,432
    float*          lamp   = (float*)(w + 155189248);              // 32

    cast_x_kernel<<<2048, 256, 0, stream>>>(x, xb);
    transpose_cast<<<dim3(16, 16, 8), 256, 0, stream>>>(Wq, wqkv_t,           512, 512);
    transpose_cast<<<dim3(16, 16, 8), 256, 0, stream>>>(Wk, wqkv_t + 2097152, 512, 512);
    transpose_cast<<<dim3(16, 16, 8), 256, 0, stream>>>(Wv, wqkv_t + 4194304, 512, 512);
    transpose_cast<<<dim3(16, 128, 1), 256, 0, stream>>>(Wo, wo_t, 4096, 512);
    lam_kernel<<<8, 64, 0, stream>>>(lq1, lk1, lq2, lk2, lamI, lamp);

    gemm_qkv_kernel<<<dim3(32, 96), 256, 0, stream>>>(xb, wqkv_t, bq, bk, bv, qws, kws, vtws);
    attn_kernel<<<dim3(64, 16), 256, 0, stream>>>(qws, kws, vtws, lamp, rmsw, oa);
    gemm_out_kernel<<<dim3(32, 4), 256, 0, stream>>>(oa, wo_t, bo, (float*)d_out);
}

// Round 5
// 947.048 us; speedup vs baseline: 2.4151x; 2.1563x over previous
//
#include <hip/hip_runtime.h>
#include <hip/hip_bf16.h>

// Differential multi-head self-attention, MI355X bf16 MFMA pipeline.
// B=2 S=2048 E=512 H=8 D=512, half=256, scale=1/16 (folded into q cast).

typedef __attribute__((ext_vector_type(8))) short short8_t;   // 8 bf16
typedef __attribute__((ext_vector_type(4))) float f32x4;

#define AS1 __attribute__((address_space(1)))
#define AS3 __attribute__((address_space(3)))

__device__ __forceinline__ f32x4 mfma16(short8_t a, short8_t b, f32x4 c) {
    return __builtin_amdgcn_mfma_f32_16x16x32_bf16(a, b, c, 0, 0, 0);
}

__device__ __forceinline__ float grp16_max(float v) {
    v = fmaxf(v, __shfl_xor(v, 1));
    v = fmaxf(v, __shfl_xor(v, 2));
    v = fmaxf(v, __shfl_xor(v, 4));
    v = fmaxf(v, __shfl_xor(v, 8));
    return v;
}
__device__ __forceinline__ float grp16_sum(float v) {
    v += __shfl_xor(v, 1);
    v += __shfl_xor(v, 2);
    v += __shfl_xor(v, 4);
    v += __shfl_xor(v, 8);
    return v;
}

// ---------------- small prep kernels ----------------

__global__ void cast_x_kernel(const float* __restrict__ in, __hip_bfloat16* __restrict__ out) {
    const int i = (blockIdx.x * 256 + threadIdx.x) * 4;
    const float4 v = *reinterpret_cast<const float4*>(in + i);
    __align__(8) __hip_bfloat16 t[4];
    t[0] = __float2bfloat16(v.x); t[1] = __float2bfloat16(v.y);
    t[2] = __float2bfloat16(v.z); t[3] = __float2bfloat16(v.w);
    *reinterpret_cast<ushort4*>(out + i) = *reinterpret_cast<const ushort4*>(t);
}

// in: batch x R x C fp32  ->  out: batch x C x R bf16
__global__ void transpose_cast(const float* __restrict__ in, __hip_bfloat16* __restrict__ out,
                               int R, int C) {
    __shared__ float tile[32][33];
    const int c0 = blockIdx.x * 32, r0 = blockIdx.y * 32;
    const size_t boff = (size_t)blockIdx.z * R * C;
    const int tx = threadIdx.x & 31, ty = threadIdx.x >> 5; // ty 0..7
#pragma unroll
    for (int i = 0; i < 4; ++i)
        tile[ty + i * 8][tx] = in[boff + (size_t)(r0 + ty + i * 8) * C + c0 + tx];
    __syncthreads();
#pragma unroll
    for (int i = 0; i < 4; ++i)
        out[boff + (size_t)(c0 + ty + i * 8) * R + r0 + tx] = __float2bfloat16(tile[tx][ty + i * 8]);
}

__global__ void lam_kernel(const float* __restrict__ lq1, const float* __restrict__ lk1,
                           const float* __restrict__ lq2, const float* __restrict__ lk2,
                           const float* __restrict__ lam_init, float* __restrict__ lam) {
    const int h = blockIdx.x, l = threadIdx.x;
    float s1 = 0.f, s2 = 0.f;
    for (int j = l; j < 512; j += 64) {
        s1 += lq1[h * 512 + j] * lk1[h * 512 + j];
        s2 += lq2[h * 512 + j] * lk2[h * 512 + j];
    }
#pragma unroll
    for (int m = 1; m < 64; m <<= 1) { s1 += __shfl_xor(s1, m); s2 += __shfl_xor(s2, m); }
    if (l == 0) lam[h] = expf(s1) - expf(s2) + lam_init[h];
}

// ---------------- shared 128x128 GEMM core (bf16, B^T layout) ----------------

__device__ __forceinline__ void gemm_core(const __hip_bfloat16* __restrict__ A,
                                          const __hip_bfloat16* __restrict__ Bt,
                                          int Kdim, int m0, int n0,
                                          __hip_bfloat16* As, __hip_bfloat16* Bs,
                                          f32x4 acc[4][4]) {
    const int tid = threadIdx.x;
    const int lane = tid & 63;
    const int r16 = lane & 15, g4 = lane >> 4;
    const int wave = tid >> 6, wm = wave & 1, wn = wave >> 1;
    const int srow = tid >> 3;            // 0..31
    const int scol = (tid & 7) * 8;       // 0..56

    for (int k0 = 0; k0 < Kdim; k0 += 64) {
        __syncthreads();
#pragma unroll
        for (int rr = 0; rr < 4; ++rr) {
            const int row = srow + rr * 32;
            short8_t av = *reinterpret_cast<const short8_t*>(A + (size_t)(m0 + row) * Kdim + k0 + scol);
            short8_t bv = *reinterpret_cast<const short8_t*>(Bt + (size_t)(n0 + row) * Kdim + k0 + scol);
            const int wb = (row * 128 + scol * 2) ^ ((row & 7) << 4);
            *reinterpret_cast<short8_t*>((char*)As + wb) = av;
            *reinterpret_cast<short8_t*>((char*)Bs + wb) = bv;
        }
        __syncthreads();
#pragma unroll
        for (int kc = 0; kc < 2; ++kc) {
            short8_t aF[4], bF[4];
#pragma unroll
            for (int i = 0; i < 4; ++i) {
                const int arow = wm * 64 + i * 16 + r16;
                aF[i] = *reinterpret_cast<const short8_t*>(
                    (char*)As + ((arow * 128 + kc * 64 + g4 * 16) ^ ((arow & 7) << 4)));
                const int brow = wn * 64 + i * 16 + r16;
                bF[i] = *reinterpret_cast<const short8_t*>(
                    (char*)Bs + ((brow * 128 + kc * 64 + g4 * 16) ^ ((brow & 7) << 4)));
            }
#pragma unroll
            for (int i = 0; i < 4; ++i)
#pragma unroll
                for (int j = 0; j < 4; ++j)
                    acc[i][j] = mfma16(aF[i], bF[j], acc[i][j]);
        }
    }
}

// QKV projection: xb[4096][512] x wqkv_t[12288][512] -> q,k [B*H][S][D], v^T [B*H][D][S] (bf16).
// q is pre-scaled by 1/16.
__global__ __launch_bounds__(256, 2)
void gemm_qkv_kernel(const __hip_bfloat16* __restrict__ xb,
                     const __hip_bfloat16* __restrict__ wt,
                     const float* __restrict__ bq, const float* __restrict__ bk,
                     const float* __restrict__ bv,
                     __hip_bfloat16* __restrict__ qo, __hip_bfloat16* __restrict__ ko,
                     __hip_bfloat16* __restrict__ vo) {
    __shared__ __align__(16) __hip_bfloat16 As[128 * 64];
    __shared__ __align__(16) __hip_bfloat16 Bs[128 * 64];
    f32x4 acc[4][4];
    const f32x4 z4 = {0.f, 0.f, 0.f, 0.f};
#pragma unroll
    for (int i = 0; i < 4; ++i)
#pragma unroll
        for (int j = 0; j < 4; ++j) acc[i][j] = z4;

    const int m0 = blockIdx.x * 128;
    const int nt = blockIdx.y;
    gemm_core(xb, wt, 512, m0, nt * 128, As, Bs, acc);

    const int which = nt >> 5, hh = (nt >> 2) & 7, dbase = (nt & 3) * 128;
    const int tid = threadIdx.x, lane = tid & 63, wave = tid >> 6;
    const int r16 = lane & 15, g4 = lane >> 4, wm = wave & 1, wn = wave >> 1;
    const int b = m0 >> 11;

    if (which == 2) {
        // V^T: [b*8+h][d][s], 4 consecutive s per fragment -> ushort4 store
#pragma unroll
        for (int i = 0; i < 4; ++i) {
#pragma unroll
            for (int j = 0; j < 4; ++j) {
                const int d = dbase + wn * 64 + j * 16 + r16;
                const float bias = bv[hh * 512 + d];
                const int s0 = (m0 & 2047) + wm * 64 + i * 16 + g4 * 4;
                __align__(8) __hip_bfloat16 t4[4];
#pragma unroll
                for (int r = 0; r < 4; ++r) t4[r] = __float2bfloat16(acc[i][j][r] + bias);
                *reinterpret_cast<ushort4*>(vo + ((size_t)(b * 8 + hh) * 512 + d) * 2048 + s0) =
                    *reinterpret_cast<const ushort4*>(t4);
            }
        }
    } else {
        __hip_bfloat16* outp = which == 0 ? qo : ko;
        const float* bp = which == 0 ? bq : bk;
        const float mul = which == 0 ? 0.0625f : 1.0f;
#pragma unroll
        for (int i = 0; i < 4; ++i) {
#pragma unroll
            for (int j = 0; j < 4; ++j) {
                const int d = dbase + wn * 64 + j * 16 + r16;
                const float bias = bp[hh * 512 + d];
#pragma unroll
                for (int r = 0; r < 4; ++r) {
                    const int s = (m0 & 2047) + wm * 64 + i * 16 + g4 * 4 + r;
                    outp[((size_t)(b * 8 + hh) * 2048 + s) * 512 + d] =
                        __float2bfloat16((acc[i][j][r] + bias) * mul);
                }
            }
        }
    }
}

// Output projection: o_attn[4096][4096] x wo_t[512][4096] -> out fp32 [4096][512] (+bo)
__global__ __launch_bounds__(256, 2)
void gemm_out_kernel(const __hip_bfloat16* __restrict__ oa,
                     const __hip_bfloat16* __restrict__ wot,
                     const float* __restrict__ bo,
                     float* __restrict__ out) {
    __shared__ __align__(16) __hip_bfloat16 As[128 * 64];
    __shared__ __align__(16) __hip_bfloat16 Bs[128 * 64];
    f32x4 acc[4][4];
    const f32x4 z4 = {0.f, 0.f, 0.f, 0.f};
#pragma unroll
    for (int i = 0; i < 4; ++i)
#pragma unroll
        for (int j = 0; j < 4; ++j) acc[i][j] = z4;

    const int m0 = blockIdx.x * 128, n0 = blockIdx.y * 128;
    gemm_core(oa, wot, 4096, m0, n0, As, Bs, acc);

    const int tid = threadIdx.x, lane = tid & 63, wave = tid >> 6;
    const int r16 = lane & 15, g4 = lane >> 4, wm = wave & 1, wn = wave >> 1;
#pragma unroll
    for (int i = 0; i < 4; ++i) {
#pragma unroll
        for (int j = 0; j < 4; ++j) {
            const int n = n0 + wn * 64 + j * 16 + r16;
            const float bias = bo[n];
#pragma unroll
            for (int r = 0; r < 4; ++r) {
                const int m = m0 + wm * 64 + i * 16 + g4 * 4 + r;
                out[(size_t)m * 512 + n] = acc[i][j][r] + bias;
            }
        }
    }
}

// ---------------- differential flash attention ----------------
// grid (S/64=32, B*H=16), 512 threads (8 waves). QBLK=64 rows, KVBLK=32 keys.
// waves 0-3: s1 (d 0..255), rows wrow*16..+16; waves 4-7: s2 (d 256..511).
// Each wave owns a 64-wide D-slice of both O accumulators (all 64 rows).
// K/V^T double-buffered in LDS via global_load_lds + counted vmcnt prefetch
// (raw s_barrier in the loop; __syncthreads would drain vmcnt(0)).

__global__ __launch_bounds__(512, 2)
void attn_kernel(const __hip_bfloat16* __restrict__ qg,
                 const __hip_bfloat16* __restrict__ kg,
                 const __hip_bfloat16* __restrict__ vtg,
                 const float* __restrict__ lam,
                 const float* __restrict__ rms_w,
                 __hip_bfloat16* __restrict__ o_attn) {
    __shared__ __align__(16) __hip_bfloat16 Ks[2][32 * 512];  // [t][d], byte ^ ((t&7)<<4)
    __shared__ __align__(16) __hip_bfloat16 Vs[2][512 * 32];  // [d][t], byte ^ ((d&7)<<4)
    __shared__ __align__(16) __hip_bfloat16 P1[64 * 40];
    __shared__ __align__(16) __hip_bfloat16 P2[64 * 40];
    __shared__ float F1[64], F2[64], L1[64], L2[64], SSQ[8][64];

    const int tid = threadIdx.x;
    const int wave = tid >> 6, lane = tid & 63;
    const int r16 = lane & 15, g4 = lane >> 4;
    const int qtile = gridDim.x - 1 - blockIdx.x;   // long blocks first
    const int bh = blockIdx.y;
    const int h = bh & 7;
    const int q0 = qtile * 64;
    const int mat = wave >> 2, wrow = wave & 3;
    const size_t bh_off = (size_t)bh * 2048 * 512;

    // Q fragments: this wave's 16 rows x 256 d (its half), k-chunks of 32
    short8_t qA[8];
    {
        const int row = q0 + wrow * 16 + r16;
        const __hip_bfloat16* qp = qg + bh_off + (size_t)row * 512 + mat * 256 + g4 * 8;
#pragma unroll
        for (int kk = 0; kk < 8; ++kk)
            qA[kk] = *reinterpret_cast<const short8_t*>(qp + kk * 32);
    }

    f32x4 O1[4][4], O2[4][4];
    const f32x4 z4 = {0.f, 0.f, 0.f, 0.f};
#pragma unroll
    for (int mq = 0; mq < 4; ++mq)
#pragma unroll
        for (int n = 0; n < 4; ++n) { O1[mq][n] = z4; O2[mq][n] = z4; }

    float m_run[4], l_run[4];
#pragma unroll
    for (int r = 0; r < 4; ++r) { m_run[r] = -1e30f; l_run[r] = 0.f; }

    // V^T staging: per-lane pre-swizzled global source offsets (elements)
    const int b2v = (lane >> 4) & 1;
    const int vdrel = (lane >> 2) ^ b2v;
    const int vcs = (lane & 3) ^ (((lane >> 2) & 3) ^ b2v);
    const int voff = vdrel * 2048 + vcs * 8;

    const __hip_bfloat16* kbase0 = kg + bh_off;
    const __hip_bfloat16* vbase0 = vtg + bh_off;

    // stage KV tile `it` into buffer `buf`: 8 global_load_lds per wave (4 K + 4 V)
    auto STAGE = [&](int buf, int it) {
        const int kv0 = it * 32;
        const __hip_bfloat16* kbase = kbase0 + (size_t)kv0 * 512;
        const __hip_bfloat16* vbase = vbase0 + kv0;
#pragma unroll
        for (int rr = 0; rr < 4; ++rr) {
            const int t = wave * 4 + rr;
            __builtin_amdgcn_global_load_lds(
                (const AS1 void*)(kbase + (size_t)t * 512 + ((lane ^ (t & 7)) << 3)),
                (AS3 void*)((char*)Ks[buf] + t * 1024), 16, 0, 0);
        }
#pragma unroll
        for (int p = 0; p < 4; ++p) {
            const int g = p * 8 + wave;
            __builtin_amdgcn_global_load_lds(
                (const AS1 void*)(vbase + (size_t)g * 16 * 2048 + voff),
                (AS3 void*)((char*)Vs[buf] + g * 1024), 16, 0, 0);
        }
    };

    const int nkv = 2 * qtile + 2;
    STAGE(0, 0);
    for (int it = 0; it < nkv; ++it) {
        const int cur = it & 1;
        const int kv0 = it * 32;
        if (it + 1 < nkv) {
            STAGE(cur ^ 1, it + 1);
            asm volatile("s_waitcnt vmcnt(8)" ::: "memory");   // current tile's 8 done
        } else {
            asm volatile("s_waitcnt vmcnt(0)" ::: "memory");
        }
        __builtin_amdgcn_s_barrier();
        __builtin_amdgcn_sched_barrier(0);

        // scores for this wave's 16 rows (2 key-frags) over its d-half
        f32x4 sc0 = z4, sc1 = z4;
#pragma unroll
        for (int kk = 0; kk < 8; ++kk) {
            const int d = mat * 256 + kk * 32 + g4 * 8;
            const int b0 = ((r16 * 512 + d) * 2) ^ ((r16 & 7) << 4);
            short8_t kf0 = *reinterpret_cast<const short8_t*>((char*)Ks[cur] + b0);
            sc0 = mfma16(qA[kk], kf0, sc0);
            const int trow = 16 + r16;
            const int b1 = ((trow * 512 + d) * 2) ^ ((trow & 7) << 4);
            short8_t kf1 = *reinterpret_cast<const short8_t*>((char*)Ks[cur] + b1);
            sc1 = mfma16(qA[kk], kf1, sc1);
        }

        // causal mask + online softmax (rows owned wave-locally)
        const int srow_base = q0 + wrow * 16 + g4 * 4;
        float tmax[4];
#pragma unroll
        for (int r = 0; r < 4; ++r) {
            float x0 = sc0[r], x1 = sc1[r];
            const int srow = srow_base + r;
            if (kv0 + r16 > srow)      x0 = -1e30f;
            if (kv0 + 16 + r16 > srow) x1 = -1e30f;
            sc0[r] = x0; sc1[r] = x1;
            tmax[r] = grp16_max(fmaxf(x0, x1));
        }
        float fr[4];
#pragma unroll
        for (int r = 0; r < 4; ++r) {
            const float mnew = fmaxf(m_run[r], tmax[r]);
            fr[r] = __expf(m_run[r] - mnew);
            m_run[r] = mnew;
            const float e0 = __expf(sc0[r] - mnew);
            const float e1 = __expf(sc1[r] - mnew);
            sc0[r] = e0; sc1[r] = e1;
            l_run[r] = l_run[r] * fr[r] + grp16_sum(e0 + e1);
        }
        __hip_bfloat16* Pm = (mat == 0) ? P1 : P2;
        float* Fm = (mat == 0) ? F1 : F2;
#pragma unroll
        for (int r = 0; r < 4; ++r) {
            const int prow = wrow * 16 + g4 * 4 + r;
            Pm[prow * 40 + r16]      = __float2bfloat16(sc0[r]);
            Pm[prow * 40 + 16 + r16] = __float2bfloat16(sc1[r]);
            if (r16 == 0) Fm[prow] = fr[r];
        }
        asm volatile("s_waitcnt lgkmcnt(0)" ::: "memory");
        __builtin_amdgcn_s_barrier();      // P/F ready
        __builtin_amdgcn_sched_barrier(0);

        // PV: each wave does its 64-wide D slice, all 64 rows, both mats
        short8_t vB[4];
#pragma unroll
        for (int n = 0; n < 4; ++n) {
            const int d = wave * 64 + n * 16 + r16;
            const int rb = (d * 64 + g4 * 16) ^ ((r16 & 7) << 4);
            vB[n] = *reinterpret_cast<const short8_t*>((const char*)Vs[cur] + rb);
        }
#pragma unroll
        for (int mq = 0; mq < 4; ++mq) {
            const short8_t pa1 = *reinterpret_cast<const short8_t*>(
                (const char*)P1 + ((mq * 16 + r16) * 40 + g4 * 8) * 2);
            const short8_t pa2 = *reinterpret_cast<const short8_t*>(
                (const char*)P2 + ((mq * 16 + r16) * 40 + g4 * 8) * 2);
#pragma unroll
            for (int r = 0; r < 4; ++r) {
                const int rm = mq * 16 + g4 * 4 + r;
                const float f = F1[rm];
                if (f != 1.0f) {
#pragma unroll
                    for (int n = 0; n < 4; ++n) O1[mq][n][r] *= f;
                }
                const float g = F2[rm];
                if (g != 1.0f) {
#pragma unroll
                    for (int n = 0; n < 4; ++n) O2[mq][n][r] *= g;
                }
            }
#pragma unroll
            for (int n = 0; n < 4; ++n) {
                O1[mq][n] = mfma16(pa1, vB[n], O1[mq][n]);
                O2[mq][n] = mfma16(pa2, vB[n], O2[mq][n]);
            }
        }
        asm volatile("s_waitcnt lgkmcnt(0)" ::: "memory");
        __builtin_amdgcn_s_barrier();      // PV reads done; next STAGE may overwrite cur
        __builtin_amdgcn_sched_barrier(0);
    }

    // epilogue: publish l, combine, RMS norm, write bf16 o_attn [B,S,H*D]
    {
        float* Lm = (mat == 0) ? L1 : L2;
        if (r16 == 0) {
#pragma unroll
            for (int r = 0; r < 4; ++r) Lm[wrow * 16 + g4 * 4 + r] = l_run[r];
        }
    }
    __syncthreads();
    const float lam_h = lam[h];
    float inv1[4][4], inv2[4][4];
#pragma unroll
    for (int mq = 0; mq < 4; ++mq)
#pragma unroll
        for (int r = 0; r < 4; ++r) {
            const int rm = mq * 16 + g4 * 4 + r;
            inv1[mq][r] = 1.0f / L1[rm];
            inv2[mq][r] = lam_h / L2[rm];
        }
    float ssq[4][4];
#pragma unroll
    for (int mq = 0; mq < 4; ++mq)
#pragma unroll
        for (int r = 0; r < 4; ++r) ssq[mq][r] = 0.f;
#pragma unroll
    for (int mq = 0; mq < 4; ++mq)
#pragma unroll
        for (int n = 0; n < 4; ++n)
#pragma unroll
            for (int r = 0; r < 4; ++r) {
                const float val = O1[mq][n][r] * inv1[mq][r] - O2[mq][n][r] * inv2[mq][r];
                O1[mq][n][r] = val;
                ssq[mq][r] += val * val;
            }
#pragma unroll
    for (int mq = 0; mq < 4; ++mq)
#pragma unroll
        for (int r = 0; r < 4; ++r) {
            ssq[mq][r] = grp16_sum(ssq[mq][r]);
            if (r16 == 0) SSQ[wave][mq * 16 + g4 * 4 + r] = ssq[mq][r];
        }
    __syncthreads();
    float rsc[4][4];
#pragma unroll
    for (int mq = 0; mq < 4; ++mq)
#pragma unroll
        for (int r = 0; r < 4; ++r) {
            const int rm = mq * 16 + g4 * 4 + r;
            float tot = 0.f;
#pragma unroll
            for (int w2 = 0; w2 < 8; ++w2) tot += SSQ[w2][rm];
            rsc[mq][r] = rsqrtf(tot * (1.0f / 512.0f) + 1.1920929e-7f) * (1.0f - 0.8f);
        }
    const int b = bh >> 3;
#pragma unroll
    for (int n = 0; n < 4; ++n) {
        const int d = wave * 64 + n * 16 + r16;
        const float rw = rms_w[h * 512 + d];
#pragma unroll
        for (int mq = 0; mq < 4; ++mq)
#pragma unroll
            for (int r = 0; r < 4; ++r) {
                const int srow = q0 + mq * 16 + g4 * 4 + r;
                o_attn[(size_t)(b * 2048 + srow) * 4096 + h * 512 + d] =
                    __float2bfloat16(O1[mq][n][r] * rsc[mq][r] * rw);
            }
    }
}

// ---------------- launch ----------------

extern "C" void kernel_launch(void* const* d_in, const int* in_sizes, int n_in,
                              void* d_out, int out_size, void* d_ws, size_t ws_size,
                              hipStream_t stream) {
    const float* x    = (const float*)d_in[0];
    const float* Wq   = (const float*)d_in[2];
    const float* bq   = (const float*)d_in[3];
    const float* Wk   = (const float*)d_in[4];
    const float* bk   = (const float*)d_in[5];
    const float* Wv   = (const float*)d_in[6];
    const float* bv   = (const float*)d_in[7];
    const float* lq1  = (const float*)d_in[8];
    const float* lk1  = (const float*)d_in[9];
    const float* lq2  = (const float*)d_in[10];
    const float* lk2  = (const float*)d_in[11];
    const float* lamI = (const float*)d_in[12];
    const float* rmsw = (const float*)d_in[13];
    const float* Wo   = (const float*)d_in[14];
    const float* bo   = (const float*)d_in[15];

    char* w = (char*)d_ws;
    __hip_bfloat16* xb     = (__hip_bfloat16*)(w);                 //  4,194,304
    __hip_bfloat16* wqkv_t = (__hip_bfloat16*)(w + 4194304);       // 12,582,912
    __hip_bfloat16* wo_t   = (__hip_bfloat16*)(w + 16777216);      //  4,194,304
    __hip_bfloat16* qws    = (__hip_bfloat16*)(w + 20971520);      // 33,554,432
    __hip_bfloat16* kws    = (__hip_bfloat16*)(w + 54525952);      // 33,554,432
    __hip_bfloat16* vtws   = (__hip_bfloat16*)(w + 88080384);      // 33,554,432 (V^T)
    __hip_bfloat16* oa     = (__hip_bfloat16*)(w + 121634816);     // 33,554,432
    float*          lamp   = (float*)(w + 155189248);              // 32

    cast_x_kernel<<<2048, 256, 0, stream>>>(x, xb);
    transpose_cast<<<dim3(16, 16, 8), 256, 0, stream>>>(Wq, wqkv_t,           512, 512);
    transpose_cast<<<dim3(16, 16, 8), 256, 0, stream>>>(Wk, wqkv_t + 2097152, 512, 512);
    transpose_cast<<<dim3(16, 16, 8), 256, 0, stream>>>(Wv, wqkv_t + 4194304, 512, 512);
    transpose_cast<<<dim3(16, 128, 1), 256, 0, stream>>>(Wo, wo_t, 4096, 512);
    lam_kernel<<<8, 64, 0, stream>>>(lq1, lk1, lq2, lk2, lamI, lamp);

    gemm_qkv_kernel<<<dim3(32, 96), 256, 0, stream>>>(xb, wqkv_t, bq, bk, bv, qws, kws, vtws);
    attn_kernel<<<dim3(32, 16), 512, 0, stream>>>(qws, kws, vtws, lamp, rmsw, oa);
    gemm_out_kernel<<<dim3(32, 4), 256, 0, stream>>>(oa, wo_t, bo, (float*)d_out);
}

// Round 8
// 661.834 us; speedup vs baseline: 3.4559x; 1.4309x over previous
//
#include <hip/hip_runtime.h>
#include <hip/hip_bf16.h>

// Differential multi-head self-attention, MI355X bf16 MFMA pipeline.
// B=2 S=2048 E=512 H=8 D=512, half=256, scale=1/16 (folded into q cast).

typedef __attribute__((ext_vector_type(8))) short short8_t;   // 8 bf16
typedef __attribute__((ext_vector_type(4))) float f32x4;

#define AS1 __attribute__((address_space(1)))
#define AS3 __attribute__((address_space(3)))

__device__ __forceinline__ f32x4 mfma16(short8_t a, short8_t b, f32x4 c) {
    return __builtin_amdgcn_mfma_f32_16x16x32_bf16(a, b, c, 0, 0, 0);
}

__device__ __forceinline__ float grp16_max(float v) {
    v = fmaxf(v, __shfl_xor(v, 1));
    v = fmaxf(v, __shfl_xor(v, 2));
    v = fmaxf(v, __shfl_xor(v, 4));
    v = fmaxf(v, __shfl_xor(v, 8));
    return v;
}
__device__ __forceinline__ float grp16_sum(float v) {
    v += __shfl_xor(v, 1);
    v += __shfl_xor(v, 2);
    v += __shfl_xor(v, 4);
    v += __shfl_xor(v, 8);
    return v;
}

// ---------------- small prep kernels ----------------

__global__ void cast_x_kernel(const float* __restrict__ in, __hip_bfloat16* __restrict__ out) {
    const int i = (blockIdx.x * 256 + threadIdx.x) * 4;
    const float4 v = *reinterpret_cast<const float4*>(in + i);
    __align__(8) __hip_bfloat16 t[4];
    t[0] = __float2bfloat16(v.x); t[1] = __float2bfloat16(v.y);
    t[2] = __float2bfloat16(v.z); t[3] = __float2bfloat16(v.w);
    *reinterpret_cast<ushort4*>(out + i) = *reinterpret_cast<const ushort4*>(t);
}

// in: batch x R x C fp32  ->  out: batch x C x R bf16
__global__ void transpose_cast(const float* __restrict__ in, __hip_bfloat16* __restrict__ out,
                               int R, int C) {
    __shared__ float tile[32][33];
    const int c0 = blockIdx.x * 32, r0 = blockIdx.y * 32;
    const size_t boff = (size_t)blockIdx.z * R * C;
    const int tx = threadIdx.x & 31, ty = threadIdx.x >> 5; // ty 0..7
#pragma unroll
    for (int i = 0; i < 4; ++i)
        tile[ty + i * 8][tx] = in[boff + (size_t)(r0 + ty + i * 8) * C + c0 + tx];
    __syncthreads();
#pragma unroll
    for (int i = 0; i < 4; ++i)
        out[boff + (size_t)(c0 + ty + i * 8) * R + r0 + tx] = __float2bfloat16(tile[tx][ty + i * 8]);
}

__global__ void lam_kernel(const float* __restrict__ lq1, const float* __restrict__ lk1,
                           const float* __restrict__ lq2, const float* __restrict__ lk2,
                           const float* __restrict__ lam_init, float* __restrict__ lam) {
    const int h = blockIdx.x, l = threadIdx.x;
    float s1 = 0.f, s2 = 0.f;
    for (int j = l; j < 512; j += 64) {
        s1 += lq1[h * 512 + j] * lk1[h * 512 + j];
        s2 += lq2[h * 512 + j] * lk2[h * 512 + j];
    }
#pragma unroll
    for (int m = 1; m < 64; m <<= 1) { s1 += __shfl_xor(s1, m); s2 += __shfl_xor(s2, m); }
    if (l == 0) lam[h] = expf(s1) - expf(s2) + lam_init[h];
}

// ---------------- shared 128x128 GEMM core (bf16, B^T layout) ----------------

__device__ __forceinline__ void gemm_core(const __hip_bfloat16* __restrict__ A,
                                          const __hip_bfloat16* __restrict__ Bt,
                                          int Kdim, int m0, int n0,
                                          __hip_bfloat16* As, __hip_bfloat16* Bs,
                                          f32x4 acc[4][4]) {
    const int tid = threadIdx.x;
    const int lane = tid & 63;
    const int r16 = lane & 15, g4 = lane >> 4;
    const int wave = tid >> 6, wm = wave & 1, wn = wave >> 1;
    const int srow = tid >> 3;            // 0..31
    const int scol = (tid & 7) * 8;       // 0..56

    for (int k0 = 0; k0 < Kdim; k0 += 64) {
        __syncthreads();
#pragma unroll
        for (int rr = 0; rr < 4; ++rr) {
            const int row = srow + rr * 32;
            short8_t av = *reinterpret_cast<const short8_t*>(A + (size_t)(m0 + row) * Kdim + k0 + scol);
            short8_t bv = *reinterpret_cast<const short8_t*>(Bt + (size_t)(n0 + row) * Kdim + k0 + scol);
            const int wb = (row * 128 + scol * 2) ^ ((row & 7) << 4);
            *reinterpret_cast<short8_t*>((char*)As + wb) = av;
            *reinterpret_cast<short8_t*>((char*)Bs + wb) = bv;
        }
        __syncthreads();
#pragma unroll
        for (int kc = 0; kc < 2; ++kc) {
            short8_t aF[4], bF[4];
#pragma unroll
            for (int i = 0; i < 4; ++i) {
                const int arow = wm * 64 + i * 16 + r16;
                aF[i] = *reinterpret_cast<const short8_t*>(
                    (char*)As + ((arow * 128 + kc * 64 + g4 * 16) ^ ((arow & 7) << 4)));
                const int brow = wn * 64 + i * 16 + r16;
                bF[i] = *reinterpret_cast<const short8_t*>(
                    (char*)Bs + ((brow * 128 + kc * 64 + g4 * 16) ^ ((brow & 7) << 4)));
            }
#pragma unroll
            for (int i = 0; i < 4; ++i)
#pragma unroll
                for (int j = 0; j < 4; ++j)
                    acc[i][j] = mfma16(aF[i], bF[j], acc[i][j]);
        }
    }
}

// QKV projection: xb[4096][512] x wqkv_t[12288][512] -> q,k [B*H][S][D], v^T [B*H][D][S] (bf16).
// q is pre-scaled by 1/16.
__global__ __launch_bounds__(256, 2)
void gemm_qkv_kernel(const __hip_bfloat16* __restrict__ xb,
                     const __hip_bfloat16* __restrict__ wt,
                     const float* __restrict__ bq, const float* __restrict__ bk,
                     const float* __restrict__ bv,
                     __hip_bfloat16* __restrict__ qo, __hip_bfloat16* __restrict__ ko,
                     __hip_bfloat16* __restrict__ vo) {
    __shared__ __align__(16) __hip_bfloat16 As[128 * 64];
    __shared__ __align__(16) __hip_bfloat16 Bs[128 * 64];
    f32x4 acc[4][4];
    const f32x4 z4 = {0.f, 0.f, 0.f, 0.f};
#pragma unroll
    for (int i = 0; i < 4; ++i)
#pragma unroll
        for (int j = 0; j < 4; ++j) acc[i][j] = z4;

    const int m0 = blockIdx.x * 128;
    const int nt = blockIdx.y;
    gemm_core(xb, wt, 512, m0, nt * 128, As, Bs, acc);

    const int which = nt >> 5, hh = (nt >> 2) & 7, dbase = (nt & 3) * 128;
    const int tid = threadIdx.x, lane = tid & 63, wave = tid >> 6;
    const int r16 = lane & 15, g4 = lane >> 4, wm = wave & 1, wn = wave >> 1;
    const int b = m0 >> 11;

    if (which == 2) {
        // V^T: [b*8+h][d][s], 4 consecutive s per fragment -> ushort4 store
#pragma unroll
        for (int i = 0; i < 4; ++i) {
#pragma unroll
            for (int j = 0; j < 4; ++j) {
                const int d = dbase + wn * 64 + j * 16 + r16;
                const float bias = bv[hh * 512 + d];
                const int s0 = (m0 & 2047) + wm * 64 + i * 16 + g4 * 4;
                __align__(8) __hip_bfloat16 t4[4];
#pragma unroll
                for (int r = 0; r < 4; ++r) t4[r] = __float2bfloat16(acc[i][j][r] + bias);
                *reinterpret_cast<ushort4*>(vo + ((size_t)(b * 8 + hh) * 512 + d) * 2048 + s0) =
                    *reinterpret_cast<const ushort4*>(t4);
            }
        }
    } else {
        __hip_bfloat16* outp = which == 0 ? qo : ko;
        const float* bp = which == 0 ? bq : bk;
        const float mul = which == 0 ? 0.0625f : 1.0f;
#pragma unroll
        for (int i = 0; i < 4; ++i) {
#pragma unroll
            for (int j = 0; j < 4; ++j) {
                const int d = dbase + wn * 64 + j * 16 + r16;
                const float bias = bp[hh * 512 + d];
#pragma unroll
                for (int r = 0; r < 4; ++r) {
                    const int s = (m0 & 2047) + wm * 64 + i * 16 + g4 * 4 + r;
                    outp[((size_t)(b * 8 + hh) * 2048 + s) * 512 + d] =
                        __float2bfloat16((acc[i][j][r] + bias) * mul);
                }
            }
        }
    }
}

// Output projection: o_attn[4096][4096] x wo_t[512][4096] -> out fp32 [4096][512] (+bo)
__global__ __launch_bounds__(256, 2)
void gemm_out_kernel(const __hip_bfloat16* __restrict__ oa,
                     const __hip_bfloat16* __restrict__ wot,
                     const float* __restrict__ bo,
                     float* __restrict__ out) {
    __shared__ __align__(16) __hip_bfloat16 As[128 * 64];
    __shared__ __align__(16) __hip_bfloat16 Bs[128 * 64];
    f32x4 acc[4][4];
    const f32x4 z4 = {0.f, 0.f, 0.f, 0.f};
#pragma unroll
    for (int i = 0; i < 4; ++i)
#pragma unroll
        for (int j = 0; j < 4; ++j) acc[i][j] = z4;

    const int m0 = blockIdx.x * 128, n0 = blockIdx.y * 128;
    gemm_core(oa, wot, 4096, m0, n0, As, Bs, acc);

    const int tid = threadIdx.x, lane = tid & 63, wave = tid >> 6;
    const int r16 = lane & 15, g4 = lane >> 4, wm = wave & 1, wn = wave >> 1;
#pragma unroll
    for (int i = 0; i < 4; ++i) {
#pragma unroll
        for (int j = 0; j < 4; ++j) {
            const int n = n0 + wn * 64 + j * 16 + r16;
            const float bias = bo[n];
#pragma unroll
            for (int r = 0; r < 4; ++r) {
                const int m = m0 + wm * 64 + i * 16 + g4 * 4 + r;
                out[(size_t)m * 512 + n] = acc[i][j][r] + bias;
            }
        }
    }
}

// ---------------- differential flash attention ----------------
// grid (512), 512 threads (8 waves). QBLK=64 rows, KVBLK=32 keys.
// XCD-pinned mapping: xcd = x&7 hosts bh = xcd (round 1) then bh = xcd+8
// (round 2); within an XCD, long q-tiles first. Each bh's K/V working set
// (4MB) becomes L2-resident on its XCD (4MB L2) -> staging from L2, not L3.
// waves 0-3: s1 (d 0..255); waves 4-7: s2 (d 256..511).
// K/V^T double-buffered in LDS via global_load_lds + counted vmcnt prefetch
// (raw s_barrier in the loop; __syncthreads would drain vmcnt(0)).

__global__ __launch_bounds__(512, 2)
void attn_kernel(const __hip_bfloat16* __restrict__ qg,
                 const __hip_bfloat16* __restrict__ kg,
                 const __hip_bfloat16* __restrict__ vtg,
                 const float* __restrict__ lam,
                 const float* __restrict__ rms_w,
                 __hip_bfloat16* __restrict__ o_attn) {
    __shared__ __align__(16) __hip_bfloat16 Ks[2][32 * 512];  // [t][d], byte ^ ((t&7)<<4)
    __shared__ __align__(16) __hip_bfloat16 Vs[2][512 * 32];  // [d][t], byte ^ ((d&7)<<4)
    __shared__ __align__(16) __hip_bfloat16 P1[64 * 40];
    __shared__ __align__(16) __hip_bfloat16 P2[64 * 40];
    __shared__ float F1[64], F2[64], L1[64], L2[64], SSQ[8][64];

    const int tid = threadIdx.x;
    const int wave = tid >> 6, lane = tid & 63;
    const int r16 = lane & 15, g4 = lane >> 4;
    // XCD-pinned block mapping (blockIdx.x -> XCD is round-robin %8)
    const int xcd = blockIdx.x & 7;
    const int j = blockIdx.x >> 3;           // 0..63
    const int bh = xcd + 8 * (j >> 5);       // round 1: bh=xcd; round 2: bh=xcd+8
    const int qtile = 31 - (j & 31);         // long blocks first within XCD
    const int h = bh & 7;
    const int q0 = qtile * 64;
    const int mat = wave >> 2, wrow = wave & 3;
    const size_t bh_off = (size_t)bh * 2048 * 512;

    // Q fragments: this wave's 16 rows x 256 d (its half), k-chunks of 32
    short8_t qA[8];
    {
        const int row = q0 + wrow * 16 + r16;
        const __hip_bfloat16* qp = qg + bh_off + (size_t)row * 512 + mat * 256 + g4 * 8;
#pragma unroll
        for (int kk = 0; kk < 8; ++kk)
            qA[kk] = *reinterpret_cast<const short8_t*>(qp + kk * 32);
    }

    f32x4 O1[4][4], O2[4][4];
    const f32x4 z4 = {0.f, 0.f, 0.f, 0.f};
#pragma unroll
    for (int mq = 0; mq < 4; ++mq)
#pragma unroll
        for (int n = 0; n < 4; ++n) { O1[mq][n] = z4; O2[mq][n] = z4; }

    float m_run[4], l_run[4];
#pragma unroll
    for (int r = 0; r < 4; ++r) { m_run[r] = -1e30f; l_run[r] = 0.f; }

    // V^T staging: per-lane pre-swizzled global source offsets (elements)
    const int b2v = (lane >> 4) & 1;
    const int vdrel = (lane >> 2) ^ b2v;
    const int vcs = (lane & 3) ^ (((lane >> 2) & 3) ^ b2v);
    const int voff = vdrel * 2048 + vcs * 8;

    const __hip_bfloat16* kbase0 = kg + bh_off;
    const __hip_bfloat16* vbase0 = vtg + bh_off;

    // stage KV tile `it` into buffer `buf`: 8 global_load_lds per wave (4 K + 4 V)
    auto STAGE = [&](int buf, int it) {
        const int kv0 = it * 32;
        const __hip_bfloat16* kbase = kbase0 + (size_t)kv0 * 512;
        const __hip_bfloat16* vbase = vbase0 + kv0;
#pragma unroll
        for (int rr = 0; rr < 4; ++rr) {
            const int t = wave * 4 + rr;
            __builtin_amdgcn_global_load_lds(
                (const AS1 void*)(kbase + (size_t)t * 512 + ((lane ^ (t & 7)) << 3)),
                (AS3 void*)((char*)Ks[buf] + t * 1024), 16, 0, 0);
        }
#pragma unroll
        for (int p = 0; p < 4; ++p) {
            const int g = p * 8 + wave;
            __builtin_amdgcn_global_load_lds(
                (const AS1 void*)(vbase + (size_t)g * 16 * 2048 + voff),
                (AS3 void*)((char*)Vs[buf] + g * 1024), 16, 0, 0);
        }
    };

    const int nkv = 2 * qtile + 2;
    STAGE(0, 0);
    for (int it = 0; it < nkv; ++it) {
        const int cur = it & 1;
        const int kv0 = it * 32;
        if (it + 1 < nkv) {
            STAGE(cur ^ 1, it + 1);
            asm volatile("s_waitcnt vmcnt(8)" ::: "memory");   // current tile's 8 done
        } else {
            asm volatile("s_waitcnt vmcnt(0)" ::: "memory");
        }
        __builtin_amdgcn_s_barrier();
        __builtin_amdgcn_sched_barrier(0);

        // scores for this wave's 16 rows (2 key-frags) over its d-half
        f32x4 sc0 = z4, sc1 = z4;
#pragma unroll
        for (int kk = 0; kk < 8; ++kk) {
            const int d = mat * 256 + kk * 32 + g4 * 8;
            const int b0 = ((r16 * 512 + d) * 2) ^ ((r16 & 7) << 4);
            short8_t kf0 = *reinterpret_cast<const short8_t*>((char*)Ks[cur] + b0);
            sc0 = mfma16(qA[kk], kf0, sc0);
            const int trow = 16 + r16;
            const int b1 = ((trow * 512 + d) * 2) ^ ((trow & 7) << 4);
            short8_t kf1 = *reinterpret_cast<const short8_t*>((char*)Ks[cur] + b1);
            sc1 = mfma16(qA[kk], kf1, sc1);
        }

        // causal mask + online softmax (rows owned wave-locally)
        const int srow_base = q0 + wrow * 16 + g4 * 4;
        float tmax[4];
#pragma unroll
        for (int r = 0; r < 4; ++r) {
            float x0 = sc0[r], x1 = sc1[r];
            const int srow = srow_base + r;
            if (kv0 + r16 > srow)      x0 = -1e30f;
            if (kv0 + 16 + r16 > srow) x1 = -1e30f;
            sc0[r] = x0; sc1[r] = x1;
            tmax[r] = grp16_max(fmaxf(x0, x1));
        }
        float fr[4];
#pragma unroll
        for (int r = 0; r < 4; ++r) {
            const float mnew = fmaxf(m_run[r], tmax[r]);
            fr[r] = __expf(m_run[r] - mnew);
            m_run[r] = mnew;
            const float e0 = __expf(sc0[r] - mnew);
            const float e1 = __expf(sc1[r] - mnew);
            sc0[r] = e0; sc1[r] = e1;
            l_run[r] = l_run[r] * fr[r] + grp16_sum(e0 + e1);
        }
        __hip_bfloat16* Pm = (mat == 0) ? P1 : P2;
        float* Fm = (mat == 0) ? F1 : F2;
#pragma unroll
        for (int r = 0; r < 4; ++r) {
            const int prow = wrow * 16 + g4 * 4 + r;
            Pm[prow * 40 + r16]      = __float2bfloat16(sc0[r]);
            Pm[prow * 40 + 16 + r16] = __float2bfloat16(sc1[r]);
            if (r16 == 0) Fm[prow] = fr[r];
        }
        asm volatile("s_waitcnt lgkmcnt(0)" ::: "memory");
        __builtin_amdgcn_s_barrier();      // P/F ready
        __builtin_amdgcn_sched_barrier(0);

        // PV: each wave does its 64-wide D slice, all 64 rows, both mats
        short8_t vB[4];
#pragma unroll
        for (int n = 0; n < 4; ++n) {
            const int d = wave * 64 + n * 16 + r16;
            const int rb = (d * 64 + g4 * 16) ^ ((r16 & 7) << 4);
            vB[n] = *reinterpret_cast<const short8_t*>((const char*)Vs[cur] + rb);
        }
#pragma unroll
        for (int mq = 0; mq < 4; ++mq) {
            const short8_t pa1 = *reinterpret_cast<const short8_t*>(
                (const char*)P1 + ((mq * 16 + r16) * 40 + g4 * 8) * 2);
            const short8_t pa2 = *reinterpret_cast<const short8_t*>(
                (const char*)P2 + ((mq * 16 + r16) * 40 + g4 * 8) * 2);
#pragma unroll
            for (int r = 0; r < 4; ++r) {
                const int rm = mq * 16 + g4 * 4 + r;
                const float f = F1[rm];
                if (f != 1.0f) {
#pragma unroll
                    for (int n = 0; n < 4; ++n) O1[mq][n][r] *= f;
                }
                const float g = F2[rm];
                if (g != 1.0f) {
#pragma unroll
                    for (int n = 0; n < 4; ++n) O2[mq][n][r] *= g;
                }
            }
#pragma unroll
            for (int n = 0; n < 4; ++n) {
                O1[mq][n] = mfma16(pa1, vB[n], O1[mq][n]);
                O2[mq][n] = mfma16(pa2, vB[n], O2[mq][n]);
            }
        }
        asm volatile("s_waitcnt lgkmcnt(0)" ::: "memory");
        __builtin_amdgcn_s_barrier();      // PV reads done; next STAGE may overwrite cur
        __builtin_amdgcn_sched_barrier(0);
    }

    // epilogue: publish l, combine, RMS norm, write bf16 o_attn [B,S,H*D]
    {
        float* Lm = (mat == 0) ? L1 : L2;
        if (r16 == 0) {
#pragma unroll
            for (int r = 0; r < 4; ++r) Lm[wrow * 16 + g4 * 4 + r] = l_run[r];
        }
    }
    __syncthreads();
    const float lam_h = lam[h];
    float inv1[4][4], inv2[4][4];
#pragma unroll
    for (int mq = 0; mq < 4; ++mq)
#pragma unroll
        for (int r = 0; r < 4; ++r) {
            const int rm = mq * 16 + g4 * 4 + r;
            inv1[mq][r] = 1.0f / L1[rm];
            inv2[mq][r] = lam_h / L2[rm];
        }
    float ssq[4][4];
#pragma unroll
    for (int mq = 0; mq < 4; ++mq)
#pragma unroll
        for (int r = 0; r < 4; ++r) ssq[mq][r] = 0.f;
#pragma unroll
    for (int mq = 0; mq < 4; ++mq)
#pragma unroll
        for (int n = 0; n < 4; ++n)
#pragma unroll
            for (int r = 0; r < 4; ++r) {
                const float val = O1[mq][n][r] * inv1[mq][r] - O2[mq][n][r] * inv2[mq][r];
                O1[mq][n][r] = val;
                ssq[mq][r] += val * val;
            }
#pragma unroll
    for (int mq = 0; mq < 4; ++mq)
#pragma unroll
        for (int r = 0; r < 4; ++r) {
            ssq[mq][r] = grp16_sum(ssq[mq][r]);
            if (r16 == 0) SSQ[wave][mq * 16 + g4 * 4 + r] = ssq[mq][r];
        }
    __syncthreads();
    float rsc[4][4];
#pragma unroll
    for (int mq = 0; mq < 4; ++mq)
#pragma unroll
        for (int r = 0; r < 4; ++r) {
            const int rm = mq * 16 + g4 * 4 + r;
            float tot = 0.f;
#pragma unroll
            for (int w2 = 0; w2 < 8; ++w2) tot += SSQ[w2][rm];
            rsc[mq][r] = rsqrtf(tot * (1.0f / 512.0f) + 1.1920929e-7f) * (1.0f - 0.8f);
        }
    const int b = bh >> 3;
#pragma unroll
    for (int n = 0; n < 4; ++n) {
        const int d = wave * 64 + n * 16 + r16;
        const float rw = rms_w[h * 512 + d];
#pragma unroll
        for (int mq = 0; mq < 4; ++mq)
#pragma unroll
            for (int r = 0; r < 4; ++r) {
                const int srow = q0 + mq * 16 + g4 * 4 + r;
                o_attn[(size_t)(b * 2048 + srow) * 4096 + h * 512 + d] =
                    __float2bfloat16(O1[mq][n][r] * rsc[mq][r] * rw);
            }
    }
}

// ---------------- launch ----------------

extern "C" void kernel_launch(void* const* d_in, const int* in_sizes, int n_in,
                              void* d_out, int out_size, void* d_ws, size_t ws_size,
                              hipStream_t stream) {
    const float* x    = (const float*)d_in[0];
    const float* Wq   = (const float*)d_in[2];
    const float* bq   = (const float*)d_in[3];
    const float* Wk   = (const float*)d_in[4];
    const float* bk   = (const float*)d_in[5];
    const float* Wv   = (const float*)d_in[6];
    const float* bv   = (const float*)d_in[7];
    const float* lq1  = (const float*)d_in[8];
    const float* lk1  = (const float*)d_in[9];
    const float* lq2  = (const float*)d_in[10];
    const float* lk2  = (const float*)d_in[11];
    const float* lamI = (const float*)d_in[12];
    const float* rmsw = (const float*)d_in[13];
    const float* Wo   = (const float*)d_in[14];
    const float* bo   = (const float*)d_in[15];

    char* w = (char*)d_ws;
    __hip_bfloat16* xb     = (__hip_bfloat16*)(w);                 //  4,194,304
    __hip_bfloat16* wqkv_t = (__hip_bfloat16*)(w + 4194304);       // 12,582,912
    __hip_bfloat16* wo_t   = (__hip_bfloat16*)(w + 16777216);      //  4,194,304
    __hip_bfloat16* qws    = (__hip_bfloat16*)(w + 20971520);      // 33,554,432
    __hip_bfloat16* kws    = (__hip_bfloat16*)(w + 54525952);      // 33,554,432
    __hip_bfloat16* vtws   = (__hip_bfloat16*)(w + 88080384);      // 33,554,432 (V^T)
    __hip_bfloat16* oa     = (__hip_bfloat16*)(w + 121634816);     // 33,554,432
    float*          lamp   = (float*)(w + 155189248);              // 32

    cast_x_kernel<<<2048, 256, 0, stream>>>(x, xb);
    transpose_cast<<<dim3(16, 16, 8), 256, 0, stream>>>(Wq, wqkv_t,           512, 512);
    transpose_cast<<<dim3(16, 16, 8), 256, 0, stream>>>(Wk, wqkv_t + 2097152, 512, 512);
    transpose_cast<<<dim3(16, 16, 8), 256, 0, stream>>>(Wv, wqkv_t + 4194304, 512, 512);
    transpose_cast<<<dim3(16, 128, 1), 256, 0, stream>>>(Wo, wo_t, 4096, 512);
    lam_kernel<<<8, 64, 0, stream>>>(lq1, lk1, lq2, lk2, lamI, lamp);

    gemm_qkv_kernel<<<dim3(32, 96), 256, 0, stream>>>(xb, wqkv_t, bq, bk, bv, qws, kws, vtws);
    attn_kernel<<<dim3(512), 512, 0, stream>>>(qws, kws, vtws, lamp, rmsw, oa);
    gemm_out_kernel<<<dim3(32, 4), 256, 0, stream>>>(oa, wo_t, bo, (float*)d_out);
}